// Round 1
// baseline (1267.243 us; speedup 1.0000x reference)
//
#include <hip/hip_runtime.h>
#include <math.h>

#define NNODES 20000
#define NEDGES 320000
#define HDIM   256
#define ODIM   128
#define TSTEPS 3

__device__ __forceinline__ float sigmoidf_(float x){ return 1.0f/(1.0f+expf(-x)); }

// ---------------- CSR build ----------------
__global__ void hist_kernel(const int* __restrict__ dst, int* __restrict__ deg){
  int e = blockIdx.x*blockDim.x + threadIdx.x;
  if (e < NEDGES) atomicAdd(&deg[dst[e]], 1);
}

__global__ void scan_kernel(const int* __restrict__ deg, int* __restrict__ rowptr){
  __shared__ int sdata[1024];
  __shared__ int s_carry;
  int tx = threadIdx.x;
  if (tx==0) s_carry = 0;
  __syncthreads();
  for (int base=0; base<NNODES; base+=1024){
    int i = base+tx;
    int v = (i<NNODES)? deg[i] : 0;
    sdata[tx]=v; __syncthreads();
    #pragma unroll
    for (int off=1; off<1024; off<<=1){
      int t = (tx>=off)? sdata[tx-off] : 0;
      __syncthreads();
      sdata[tx] += t;
      __syncthreads();
    }
    if (i<NNODES) rowptr[i] = s_carry + sdata[tx] - v;   // exclusive
    int tot = sdata[1023];
    __syncthreads();
    if (tx==0) s_carry += tot;
    __syncthreads();
  }
  if (tx==0) rowptr[NNODES] = s_carry;
}

__global__ void scatter_kernel(const int* __restrict__ src, const int* __restrict__ dst,
                               const int* __restrict__ rowptr, int* __restrict__ fill,
                               int* __restrict__ ssrc){
  int e = blockIdx.x*blockDim.x + threadIdx.x;
  if (e < NEDGES){
    int d = dst[e];
    int pos = rowptr[d] + atomicAdd(&fill[d], 1);
    ssrc[pos] = src[e];
  }
}

// ---------------- generic NT GEMM: C[M,Nc] = A[M,K] @ B[Nc,K]^T (+bias) ----------------
__global__ __launch_bounds__(256)
void gemm_nt_kernel(const float* __restrict__ A, const float* __restrict__ B,
                    const float* __restrict__ bias, float* __restrict__ C,
                    int M, int Nc){
  const int K = HDIM;
  __shared__ __align__(16) float As[16][68];
  __shared__ __align__(16) float Bs[16][68];
  int tx = threadIdx.x;
  int r0 = blockIdx.x*64, c0 = blockIdx.y*64;
  int rl = (tx>>4)<<2, cl = (tx&15)<<2;     // compute layout: 16x16 threads, 4x4 each
  int lr = tx>>2, lk = (tx&3)<<2;           // load layout: 64 rows x 4 k-chunks
  float acc[4][4] = {};
  for (int kt=0; kt<K; kt+=16){
    int gr = r0+lr, gc = c0+lr;
    float4 va = (gr<M) ? *(const float4*)&A[(size_t)gr*K + kt + lk] : make_float4(0,0,0,0);
    float4 vb = (gc<Nc)? *(const float4*)&B[(size_t)gc*K + kt + lk] : make_float4(0,0,0,0);
    As[lk+0][lr]=va.x; As[lk+1][lr]=va.y; As[lk+2][lr]=va.z; As[lk+3][lr]=va.w;
    Bs[lk+0][lr]=vb.x; Bs[lk+1][lr]=vb.y; Bs[lk+2][lr]=vb.z; Bs[lk+3][lr]=vb.w;
    __syncthreads();
    #pragma unroll
    for (int k=0;k<16;k++){
      float4 a4 = *(const float4*)&As[k][rl];
      float4 b4 = *(const float4*)&Bs[k][cl];
      float a[4]={a4.x,a4.y,a4.z,a4.w}, b[4]={b4.x,b4.y,b4.z,b4.w};
      #pragma unroll
      for (int i=0;i<4;i++)
        #pragma unroll
        for (int j=0;j<4;j++) acc[i][j] += a[i]*b[j];
    }
    __syncthreads();
  }
  #pragma unroll
  for (int i=0;i<4;i++){
    int gr = r0+rl+i;
    if (gr>=M) continue;
    int gc = c0+cl;
    float b0=0,b1=0,b2=0,b3=0;
    if (bias){ b0=bias[gc]; b1=bias[gc+1]; b2=bias[gc+2]; b3=bias[gc+3]; }
    float4 o = make_float4(acc[i][0]+b0, acc[i][1]+b1, acc[i][2]+b2, acc[i][3]+b3);
    *(float4*)&C[(size_t)gr*Nc + gc] = o;
  }
}

// ---------------- per-node attention logits: as[i]=xp[i]·att_src, ad[i]=xp[i]·att_dst ----------------
__global__ void alpha_kernel(const float* __restrict__ xp, const float* __restrict__ att_src,
                             const float* __restrict__ att_dst,
                             float* __restrict__ as_, float* __restrict__ ad_){
  int node = blockIdx.x*4 + (threadIdx.x>>6);
  int lane = threadIdx.x & 63;
  if (node >= NNODES) return;
  float4 v = *(const float4*)&xp[(size_t)node*HDIM + lane*4];
  float4 a = *(const float4*)&att_src[lane*4];
  float4 b = *(const float4*)&att_dst[lane*4];
  float ps = v.x*a.x + v.y*a.y + v.z*a.z + v.w*a.w;
  float pd = v.x*b.x + v.y*b.y + v.z*b.z + v.w*b.w;
  for (int off=32; off; off>>=1){ ps += __shfl_down(ps,off); pd += __shfl_down(pd,off); }
  if (lane==0){ as_[node]=ps; ad_[node]=pd; }
}

// ---------------- GAT segment softmax + aggregate (+bias +ELU) : one block per dst node ----------------
__global__ __launch_bounds__(256)
void gat_aggregate_kernel(const float* __restrict__ xp, const float* __restrict__ as_,
                          const float* __restrict__ ad_, const int* __restrict__ rowptr,
                          const int* __restrict__ ssrc, const float* __restrict__ gat_bias,
                          float* __restrict__ msg){
  int node = blockIdx.x;
  int tx = threadIdx.x;
  __shared__ float rbuf[4];
  __shared__ float s_coef[256];
  __shared__ int   s_src[256];
  int beg = rowptr[node], end = rowptr[node+1];
  float adv = ad_[node];

  // pass 1: segment max of leaky_relu(as[src]+ad[dst])
  float mx = -INFINITY;
  for (int e=beg+tx; e<end; e+=256){
    float a = as_[ssrc[e]] + adv;
    a = (a>0.f)? a : 0.01f*a;
    mx = fmaxf(mx, a);
  }
  for (int off=32; off; off>>=1) mx = fmaxf(mx, __shfl_down(mx,off));
  if ((tx&63)==0) rbuf[tx>>6] = mx;
  __syncthreads();
  mx = fmaxf(fmaxf(rbuf[0],rbuf[1]), fmaxf(rbuf[2],rbuf[3]));
  __syncthreads();

  // pass 2: denom
  float sm = 0.f;
  for (int e=beg+tx; e<end; e+=256){
    float a = as_[ssrc[e]] + adv;
    a = (a>0.f)? a : 0.01f*a;
    sm += expf(a - mx);
  }
  for (int off=32; off; off>>=1) sm += __shfl_down(sm,off);
  if ((tx&63)==0) rbuf[tx>>6] = sm;
  __syncthreads();
  sm = rbuf[0]+rbuf[1]+rbuf[2]+rbuf[3];
  float scale = 1.0f/fmaxf(sm, 1e-16f);

  // pass 3: acc[c] = sum_e coef_e * xp[src_e][c]  (coefs staged per 256-edge chunk)
  float acc = 0.f;
  for (int cb=beg; cb<end; cb+=256){
    int n = min(256, end-cb);
    __syncthreads();
    if (tx < n){
      int s = ssrc[cb+tx];
      s_src[tx] = s;
      float a = as_[s] + adv;
      a = (a>0.f)? a : 0.01f*a;
      s_coef[tx] = expf(a - mx)*scale;
    }
    __syncthreads();
    int e=0;
    for (; e+4<=n; e+=4){
      float x0 = xp[(size_t)s_src[e+0]*HDIM + tx];
      float x1 = xp[(size_t)s_src[e+1]*HDIM + tx];
      float x2 = xp[(size_t)s_src[e+2]*HDIM + tx];
      float x3 = xp[(size_t)s_src[e+3]*HDIM + tx];
      acc += s_coef[e+0]*x0; acc += s_coef[e+1]*x1;
      acc += s_coef[e+2]*x2; acc += s_coef[e+3]*x3;
    }
    for (; e<n; e++) acc += s_coef[e]*xp[(size_t)s_src[e]*HDIM + tx];
  }
  float v = acc + gat_bias[tx];
  msg[(size_t)node*HDIM + tx] = (v>0.f)? v : (expf(v)-1.0f);
}

// ---------------- fused GRU: h_new = GRU(msg, h) ; dual GEMM w/ 6 accumulator tiles ----------------
__global__ __launch_bounds__(256)
void gru_fused_kernel(const float* __restrict__ msg, const float* __restrict__ hc,
                      float* __restrict__ h_new,
                      const float* __restrict__ Wih, const float* __restrict__ Whh,
                      const float* __restrict__ bih, const float* __restrict__ bhh){
  __shared__ __align__(16) float Ms [16][68];
  __shared__ __align__(16) float Hs [16][68];
  __shared__ __align__(16) float Wri[16][68];
  __shared__ __align__(16) float Wzi[16][68];
  __shared__ __align__(16) float Wni[16][68];
  __shared__ __align__(16) float Wrh[16][68];
  __shared__ __align__(16) float Wzh[16][68];
  __shared__ __align__(16) float Wnh[16][68];
  int tx = threadIdx.x;
  int r0 = blockIdx.x*64, c0 = blockIdx.y*64;
  int rl = (tx>>4)<<2, cl = (tx&15)<<2;
  int lr = tx>>2, lk = (tx&3)<<2;
  float aXr[4][4]={}, aXz[4][4]={}, aXn[4][4]={};
  float aHr[4][4]={}, aHz[4][4]={}, aHn[4][4]={};
  for (int kt=0; kt<HDIM; kt+=16){
    int gr = r0+lr;
    float4 vm = (gr<NNODES)? *(const float4*)&msg[(size_t)gr*HDIM + kt + lk] : make_float4(0,0,0,0);
    float4 vh = (gr<NNODES)? *(const float4*)&hc [(size_t)gr*HDIM + kt + lk] : make_float4(0,0,0,0);
    int wr = c0+lr;
    float4 w0 = *(const float4*)&Wih[(size_t)(0*HDIM+wr)*HDIM + kt + lk];
    float4 w1 = *(const float4*)&Wih[(size_t)(1*HDIM+wr)*HDIM + kt + lk];
    float4 w2 = *(const float4*)&Wih[(size_t)(2*HDIM+wr)*HDIM + kt + lk];
    float4 u0 = *(const float4*)&Whh[(size_t)(0*HDIM+wr)*HDIM + kt + lk];
    float4 u1 = *(const float4*)&Whh[(size_t)(1*HDIM+wr)*HDIM + kt + lk];
    float4 u2 = *(const float4*)&Whh[(size_t)(2*HDIM+wr)*HDIM + kt + lk];
    Ms [lk+0][lr]=vm.x; Ms [lk+1][lr]=vm.y; Ms [lk+2][lr]=vm.z; Ms [lk+3][lr]=vm.w;
    Hs [lk+0][lr]=vh.x; Hs [lk+1][lr]=vh.y; Hs [lk+2][lr]=vh.z; Hs [lk+3][lr]=vh.w;
    Wri[lk+0][lr]=w0.x; Wri[lk+1][lr]=w0.y; Wri[lk+2][lr]=w0.z; Wri[lk+3][lr]=w0.w;
    Wzi[lk+0][lr]=w1.x; Wzi[lk+1][lr]=w1.y; Wzi[lk+2][lr]=w1.z; Wzi[lk+3][lr]=w1.w;
    Wni[lk+0][lr]=w2.x; Wni[lk+1][lr]=w2.y; Wni[lk+2][lr]=w2.z; Wni[lk+3][lr]=w2.w;
    Wrh[lk+0][lr]=u0.x; Wrh[lk+1][lr]=u0.y; Wrh[lk+2][lr]=u0.z; Wrh[lk+3][lr]=u0.w;
    Wzh[lk+0][lr]=u1.x; Wzh[lk+1][lr]=u1.y; Wzh[lk+2][lr]=u1.z; Wzh[lk+3][lr]=u1.w;
    Wnh[lk+0][lr]=u2.x; Wnh[lk+1][lr]=u2.y; Wnh[lk+2][lr]=u2.z; Wnh[lk+3][lr]=u2.w;
    __syncthreads();
    #pragma unroll
    for (int k=0;k<16;k++){
      float4 am4=*(const float4*)&Ms [k][rl];
      float4 ah4=*(const float4*)&Hs [k][rl];
      float4 br4=*(const float4*)&Wri[k][cl];
      float4 bz4=*(const float4*)&Wzi[k][cl];
      float4 bn4=*(const float4*)&Wni[k][cl];
      float4 cr4=*(const float4*)&Wrh[k][cl];
      float4 cz4=*(const float4*)&Wzh[k][cl];
      float4 cn4=*(const float4*)&Wnh[k][cl];
      float am[4]={am4.x,am4.y,am4.z,am4.w}, ah[4]={ah4.x,ah4.y,ah4.z,ah4.w};
      float br[4]={br4.x,br4.y,br4.z,br4.w}, bz[4]={bz4.x,bz4.y,bz4.z,bz4.w};
      float bn[4]={bn4.x,bn4.y,bn4.z,bn4.w};
      float cr[4]={cr4.x,cr4.y,cr4.z,cr4.w}, cz[4]={cz4.x,cz4.y,cz4.z,cz4.w};
      float cn[4]={cn4.x,cn4.y,cn4.z,cn4.w};
      #pragma unroll
      for (int i=0;i<4;i++)
        #pragma unroll
        for (int j=0;j<4;j++){
          aXr[i][j] += am[i]*br[j];
          aXz[i][j] += am[i]*bz[j];
          aXn[i][j] += am[i]*bn[j];
          aHr[i][j] += ah[i]*cr[j];
          aHz[i][j] += ah[i]*cz[j];
          aHn[i][j] += ah[i]*cn[j];
        }
    }
    __syncthreads();
  }
  #pragma unroll
  for (int i=0;i<4;i++){
    int gr = r0+rl+i;
    if (gr>=NNODES) continue;
    int gc0 = c0+cl;
    float4 hv4 = *(const float4*)&hc[(size_t)gr*HDIM + gc0];
    float hold[4]={hv4.x,hv4.y,hv4.z,hv4.w};
    float res[4];
    #pragma unroll
    for (int j=0;j<4;j++){
      int gc = gc0+j;
      float xr = aXr[i][j] + bih[gc];
      float xz = aXz[i][j] + bih[HDIM+gc];
      float xn = aXn[i][j] + bih[2*HDIM+gc];
      float hr = aHr[i][j] + bhh[gc];
      float hz = aHz[i][j] + bhh[HDIM+gc];
      float hn = aHn[i][j] + bhh[2*HDIM+gc];
      float r = sigmoidf_(xr+hr);
      float z = sigmoidf_(xz+hz);
      float n = tanhf(xn + r*hn);
      res[j] = (1.0f-z)*n + z*hold[j];
    }
    *(float4*)&h_new[(size_t)gr*HDIM + gc0] = make_float4(res[0],res[1],res[2],res[3]);
  }
}

// ---------------- launch ----------------
extern "C" void kernel_launch(void* const* d_in, const int* in_sizes, int n_in,
                              void* d_out, int out_size, void* d_ws, size_t ws_size,
                              hipStream_t stream) {
  const float* x_clique = (const float*)d_in[0];
  const float* W_gat    = (const float*)d_in[1];
  const float* att_src  = (const float*)d_in[2];
  const float* att_dst  = (const float*)d_in[3];
  const float* gat_bias = (const float*)d_in[4];
  const float* W_ih     = (const float*)d_in[5];
  const float* W_hh     = (const float*)d_in[6];
  const float* b_ih     = (const float*)d_in[7];
  const float* b_hh     = (const float*)d_in[8];
  const float* lin_W    = (const float*)d_in[9];
  const float* lin_b    = (const float*)d_in[10];
  const int*   eidx     = (const int*)d_in[14];
  float* out = (float*)d_out;

  const int* src = eidx;
  const int* dst = eidx + NEDGES;

  const size_t NH = (size_t)NNODES*HDIM;
  float* W = (float*)d_ws;
  float* h0  = W;
  float* h1  = W + NH;
  float* xp  = W + 2*NH;
  float* msg = W + 3*NH;
  float* as_ = W + 4*NH;
  float* ad_ = as_ + NNODES;
  int* deg    = (int*)(ad_ + NNODES);
  int* fill   = deg + NNODES;
  int* rowptr = fill + NNODES;
  int* ssrc   = rowptr + (NNODES+1);

  // CSR build (per call; graph is identical every call)
  hipMemsetAsync(deg,  0, NNODES*sizeof(int), stream);
  hipMemsetAsync(fill, 0, NNODES*sizeof(int), stream);
  hist_kernel<<<(NEDGES+255)/256, 256, 0, stream>>>(dst, deg);
  scan_kernel<<<1, 1024, 0, stream>>>(deg, rowptr);
  scatter_kernel<<<(NEDGES+255)/256, 256, 0, stream>>>(src, dst, rowptr, fill, ssrc);

  hipMemcpyAsync(h0, x_clique, NH*sizeof(float), hipMemcpyDeviceToDevice, stream);

  const int RB = (NNODES+63)/64;  // 313
  float* hc = h0;
  float* hn = h1;
  for (int t=0; t<TSTEPS; t++){
    gemm_nt_kernel<<<dim3(RB, HDIM/64), 256, 0, stream>>>(hc, W_gat, nullptr, xp, NNODES, HDIM);
    alpha_kernel<<<(NNODES+3)/4, 256, 0, stream>>>(xp, att_src, att_dst, as_, ad_);
    gat_aggregate_kernel<<<NNODES, 256, 0, stream>>>(xp, as_, ad_, rowptr, ssrc, gat_bias, msg);
    gru_fused_kernel<<<dim3(RB, HDIM/64), 256, 0, stream>>>(msg, hc, hn, W_ih, W_hh, b_ih, b_hh);
    float* tmp = hc; hc = hn; hn = tmp;
  }
  gemm_nt_kernel<<<dim3(RB, ODIM/64), 256, 0, stream>>>(hc, lin_W, lin_b, out, NNODES, ODIM);
}

// Round 2
// 750.578 us; speedup vs baseline: 1.6884x; 1.6884x over previous
//
#include <hip/hip_runtime.h>
#include <math.h>

#define NNODES 20000
#define NROWP  20096   // NNODES padded to multiple of 128 (gemm row-tile)
#define NEDGES 320000
#define HDIM   256
#define ODIM   128
#define TSTEPS 3

typedef __bf16 bf16x8 __attribute__((ext_vector_type(8)));
typedef __bf16 bf16x4 __attribute__((ext_vector_type(4)));
typedef float  f32x4  __attribute__((ext_vector_type(4)));

__device__ __forceinline__ float sigmoidf_(float x){ return 1.0f/(1.0f+expf(-x)); }

// MFMA 16x16x32 bf16 fragment load (A or B operand, NT K-major layout):
// lane l supplies row (l&15), k-chunk (l>>4)*8 .. +8  -> one 16B load.
__device__ __forceinline__ bf16x8 ld_frag(const __bf16* base, int lane){
  return *(const bf16x8*)(base + (size_t)(lane&15)*HDIM + ((lane>>4)<<3));
}

// ---------------- fp32 -> bf16 convert ----------------
__global__ void cvt_kernel(const float* __restrict__ src, __bf16* __restrict__ dst, int n4){
  int i = blockIdx.x*blockDim.x + threadIdx.x;
  if (i < n4){
    float4 v = ((const float4*)src)[i];
    bf16x4 o; o[0]=(__bf16)v.x; o[1]=(__bf16)v.y; o[2]=(__bf16)v.z; o[3]=(__bf16)v.w;
    ((bf16x4*)dst)[i] = o;
  }
}

// ---------------- CSR build ----------------
__global__ void hist_kernel(const int* __restrict__ dst, int* __restrict__ deg){
  int e = blockIdx.x*blockDim.x + threadIdx.x;
  if (e < NEDGES) atomicAdd(&deg[dst[e]], 1);
}

__global__ void scan_kernel(const int* __restrict__ deg, int* __restrict__ rowptr){
  __shared__ int sdata[1024];
  __shared__ int s_carry;
  int tx = threadIdx.x;
  if (tx==0) s_carry = 0;
  __syncthreads();
  for (int base=0; base<NNODES; base+=1024){
    int i = base+tx;
    int v = (i<NNODES)? deg[i] : 0;
    sdata[tx]=v; __syncthreads();
    #pragma unroll
    for (int off=1; off<1024; off<<=1){
      int t = (tx>=off)? sdata[tx-off] : 0;
      __syncthreads();
      sdata[tx] += t;
      __syncthreads();
    }
    if (i<NNODES) rowptr[i] = s_carry + sdata[tx] - v;   // exclusive
    int tot = sdata[1023];
    __syncthreads();
    if (tx==0) s_carry += tot;
    __syncthreads();
  }
  if (tx==0) rowptr[NNODES] = s_carry;
}

__global__ void scatter_kernel(const int* __restrict__ src, const int* __restrict__ dst,
                               const int* __restrict__ rowptr, int* __restrict__ fill,
                               int* __restrict__ ssrc){
  int e = blockIdx.x*blockDim.x + threadIdx.x;
  if (e < NEDGES){
    int d = dst[e];
    int pos = rowptr[d] + atomicAdd(&fill[d], 1);
    ssrc[pos] = src[e];
  }
}

// ---------------- generic MFMA NT GEMM: C[M,Nc] = A[M,256] @ B[Nc,256]^T ----------------
// block = 4 waves covering 128x64; wave tile 64x32 (4x2 mfma frags).
__global__ __launch_bounds__(256)
void mfma_gemm_nt(const __bf16* __restrict__ A, const __bf16* __restrict__ B,
                  const float* __restrict__ bias, __bf16* __restrict__ Cb,
                  float* __restrict__ Cf, int M, int Nc){
  int tx = threadIdx.x;
  int lane = tx & 63, w = tx >> 6;
  int r0 = blockIdx.x*128 + (w&1)*64;
  int c0 = blockIdx.y*64  + (w>>1)*32;
  f32x4 acc[4][2] = {};
  for (int k=0; k<HDIM; k+=32){
    bf16x8 a[4], b[2];
    #pragma unroll
    for (int i=0;i<4;i++) a[i] = ld_frag(A + (size_t)(r0+i*16)*HDIM + k, lane);
    #pragma unroll
    for (int j=0;j<2;j++) b[j] = ld_frag(B + (size_t)(c0+j*16)*HDIM + k, lane);
    #pragma unroll
    for (int i=0;i<4;i++)
      #pragma unroll
      for (int j=0;j<2;j++)
        acc[i][j] = __builtin_amdgcn_mfma_f32_16x16x32_bf16(a[i], b[j], acc[i][j], 0,0,0);
  }
  int rb = (lane>>4)<<2, cb = lane&15;
  #pragma unroll
  for (int i=0;i<4;i++){
    #pragma unroll
    for (int j=0;j<2;j++){
      int gc = c0 + j*16 + cb;
      float bv = bias ? bias[gc] : 0.f;
      #pragma unroll
      for (int r=0;r<4;r++){
        int gr = r0 + i*16 + rb + r;
        if (gr >= M) continue;
        float v = acc[i][j][r] + bv;
        if (Cf) Cf[(size_t)gr*Nc + gc] = v;
        if (Cb) Cb[(size_t)gr*Nc + gc] = (__bf16)v;
      }
    }
  }
}

// ---------------- attention logits from bf16 xp ----------------
__global__ void alpha_kernel(const __bf16* __restrict__ xpb, const float* __restrict__ att_src,
                             const float* __restrict__ att_dst,
                             float* __restrict__ as_, float* __restrict__ ad_){
  int node = blockIdx.x*4 + (threadIdx.x>>6);
  int lane = threadIdx.x & 63;
  if (node >= NNODES) return;
  bf16x4 v4 = *(const bf16x4*)&xpb[(size_t)node*HDIM + lane*4];
  float4 a = *(const float4*)&att_src[lane*4];
  float4 b = *(const float4*)&att_dst[lane*4];
  float v0=(float)v4[0], v1=(float)v4[1], v2=(float)v4[2], v3=(float)v4[3];
  float ps = v0*a.x + v1*a.y + v2*a.z + v3*a.w;
  float pd = v0*b.x + v1*b.y + v2*b.z + v3*b.w;
  for (int off=32; off; off>>=1){ ps += __shfl_down(ps,off); pd += __shfl_down(pd,off); }
  if (lane==0){ as_[node]=ps; ad_[node]=pd; }
}

// ---------------- GAT segment softmax + aggregate (+bias +ELU), bf16 gather ----------------
__global__ __launch_bounds__(256)
void gat_aggregate_kernel(const __bf16* __restrict__ xpb, const float* __restrict__ as_,
                          const float* __restrict__ ad_, const int* __restrict__ rowptr,
                          const int* __restrict__ ssrc, const float* __restrict__ gat_bias,
                          __bf16* __restrict__ msgb){
  int node = blockIdx.x;
  int tx = threadIdx.x;
  __shared__ float rbuf[4];
  __shared__ float s_coef[256];
  __shared__ int   s_src[256];
  int beg = rowptr[node], end = rowptr[node+1];
  float adv = ad_[node];

  // pass 1: segment max of leaky_relu
  float mx = -INFINITY;
  for (int e=beg+tx; e<end; e+=256){
    float a = as_[ssrc[e]] + adv;
    a = (a>0.f)? a : 0.01f*a;
    mx = fmaxf(mx, a);
  }
  for (int off=32; off; off>>=1) mx = fmaxf(mx, __shfl_down(mx,off));
  if ((tx&63)==0) rbuf[tx>>6] = mx;
  __syncthreads();
  mx = fmaxf(fmaxf(rbuf[0],rbuf[1]), fmaxf(rbuf[2],rbuf[3]));
  __syncthreads();

  // pass 2: denom
  float sm = 0.f;
  for (int e=beg+tx; e<end; e+=256){
    float a = as_[ssrc[e]] + adv;
    a = (a>0.f)? a : 0.01f*a;
    sm += expf(a - mx);
  }
  for (int off=32; off; off>>=1) sm += __shfl_down(sm,off);
  if ((tx&63)==0) rbuf[tx>>6] = sm;
  __syncthreads();
  sm = rbuf[0]+rbuf[1]+rbuf[2]+rbuf[3];
  float scale = 1.0f/fmaxf(sm, 1e-16f);

  // pass 3: weighted row accumulate
  float acc = 0.f;
  for (int cb=beg; cb<end; cb+=256){
    int n = min(256, end-cb);
    __syncthreads();
    if (tx < n){
      int s = ssrc[cb+tx];
      s_src[tx] = s;
      float a = as_[s] + adv;
      a = (a>0.f)? a : 0.01f*a;
      s_coef[tx] = expf(a - mx)*scale;
    }
    __syncthreads();
    int e=0;
    for (; e+4<=n; e+=4){
      float x0 = (float)xpb[(size_t)s_src[e+0]*HDIM + tx];
      float x1 = (float)xpb[(size_t)s_src[e+1]*HDIM + tx];
      float x2 = (float)xpb[(size_t)s_src[e+2]*HDIM + tx];
      float x3 = (float)xpb[(size_t)s_src[e+3]*HDIM + tx];
      acc += s_coef[e+0]*x0; acc += s_coef[e+1]*x1;
      acc += s_coef[e+2]*x2; acc += s_coef[e+3]*x3;
    }
    for (; e<n; e++) acc += s_coef[e]*(float)xpb[(size_t)s_src[e]*HDIM + tx];
  }
  float v = acc + gat_bias[tx];
  msgb[(size_t)node*HDIM + tx] = (__bf16)((v>0.f)? v : (expf(v)-1.0f));
}

// ---------------- fused GRU MFMA: 6 products (r,z,n for X and H paths) ----------------
// block = 4 waves covering 64x64 (rows x gate-cols); wave tile 32x32; 24 acc frags.
__global__ __launch_bounds__(256)
void gru_mfma_kernel(const __bf16* __restrict__ msgb, const __bf16* __restrict__ hb,
                     __bf16* __restrict__ hnb,
                     const __bf16* __restrict__ Wihb, const __bf16* __restrict__ Whhb,
                     const float* __restrict__ bih, const float* __restrict__ bhh){
  int tx = threadIdx.x;
  int lane = tx & 63, w = tx >> 6;
  int r0 = blockIdx.x*64 + (w&1)*32;
  int c0 = blockIdx.y*64 + (w>>1)*32;
  f32x4 aX[3][2][2] = {};
  f32x4 aH[3][2][2] = {};
  for (int k=0; k<HDIM; k+=32){
    bf16x8 am[2], ah[2];
    #pragma unroll
    for (int i=0;i<2;i++){
      am[i] = ld_frag(msgb + (size_t)(r0+i*16)*HDIM + k, lane);
      ah[i] = ld_frag(hb   + (size_t)(r0+i*16)*HDIM + k, lane);
    }
    #pragma unroll
    for (int g=0; g<3; g++){
      bf16x8 bi[2], bh[2];
      #pragma unroll
      for (int j=0;j<2;j++){
        size_t brow = (size_t)(g*HDIM + c0 + j*16);
        bi[j] = ld_frag(Wihb + brow*HDIM + k, lane);
        bh[j] = ld_frag(Whhb + brow*HDIM + k, lane);
      }
      #pragma unroll
      for (int i=0;i<2;i++)
        #pragma unroll
        for (int j=0;j<2;j++){
          aX[g][i][j] = __builtin_amdgcn_mfma_f32_16x16x32_bf16(am[i], bi[j], aX[g][i][j], 0,0,0);
          aH[g][i][j] = __builtin_amdgcn_mfma_f32_16x16x32_bf16(ah[i], bh[j], aH[g][i][j], 0,0,0);
        }
    }
  }
  int rb = (lane>>4)<<2, cb = lane&15;
  #pragma unroll
  for (int i=0;i<2;i++){
    #pragma unroll
    for (int j=0;j<2;j++){
      int gc = c0 + j*16 + cb;
      float bir=bih[gc], biz=bih[HDIM+gc], bin_=bih[2*HDIM+gc];
      float bhr=bhh[gc], bhz=bhh[HDIM+gc], bhn=bhh[2*HDIM+gc];
      #pragma unroll
      for (int r=0;r<4;r++){
        int gr = r0 + i*16 + rb + r;
        float hold = (float)hb[(size_t)gr*HDIM + gc];
        float rr = sigmoidf_(aX[0][i][j][r] + bir + aH[0][i][j][r] + bhr);
        float zz = sigmoidf_(aX[1][i][j][r] + biz + aH[1][i][j][r] + bhz);
        float nn = tanhf(aX[2][i][j][r] + bin_ + rr*(aH[2][i][j][r] + bhn));
        hnb[(size_t)gr*HDIM + gc] = (__bf16)((1.f-zz)*nn + zz*hold);
      }
    }
  }
}

// ---------------- launch ----------------
extern "C" void kernel_launch(void* const* d_in, const int* in_sizes, int n_in,
                              void* d_out, int out_size, void* d_ws, size_t ws_size,
                              hipStream_t stream) {
  const float* x_clique = (const float*)d_in[0];
  const float* W_gat    = (const float*)d_in[1];
  const float* att_src  = (const float*)d_in[2];
  const float* att_dst  = (const float*)d_in[3];
  const float* gat_bias = (const float*)d_in[4];
  const float* W_ih     = (const float*)d_in[5];
  const float* W_hh     = (const float*)d_in[6];
  const float* b_ih     = (const float*)d_in[7];
  const float* b_hh     = (const float*)d_in[8];
  const float* lin_W    = (const float*)d_in[9];
  const float* lin_b    = (const float*)d_in[10];
  const int*   eidx     = (const int*)d_in[14];
  float* out = (float*)d_out;

  const int* src = eidx;
  const int* dst = eidx + NEDGES;

  const size_t NHP = (size_t)NROWP*HDIM;
  __bf16* h0b  = (__bf16*)d_ws;
  __bf16* h1b  = h0b  + NHP;
  __bf16* xpb  = h1b  + NHP;
  __bf16* msgb = xpb  + NHP;
  __bf16* wgb  = msgb + NHP;                 // 256*256
  __bf16* wihb = wgb  + (size_t)HDIM*HDIM;   // 768*256
  __bf16* whhb = wihb + (size_t)3*HDIM*HDIM;
  __bf16* lwb  = whhb + (size_t)3*HDIM*HDIM; // 128*256
  float* as_   = (float*)(lwb + (size_t)ODIM*HDIM);
  float* ad_   = as_ + NNODES;
  int* deg     = (int*)(ad_ + NNODES);
  int* fill    = deg + NNODES;
  int* rowptr  = fill + NNODES;
  int* ssrc    = rowptr + (NNODES+1);

  // CSR build
  hipMemsetAsync(deg,  0, NNODES*sizeof(int), stream);
  hipMemsetAsync(fill, 0, NNODES*sizeof(int), stream);
  hist_kernel<<<(NEDGES+255)/256, 256, 0, stream>>>(dst, deg);
  scan_kernel<<<1, 1024, 0, stream>>>(deg, rowptr);
  scatter_kernel<<<(NEDGES+255)/256, 256, 0, stream>>>(src, dst, rowptr, fill, ssrc);

  // bf16 conversions (weights + initial h); zero the padded rows of h buffers
  cvt_kernel<<<(NNODES*HDIM/4+255)/256, 256, 0, stream>>>(x_clique, h0b, NNODES*HDIM/4);
  hipMemsetAsync(h0b + (size_t)NNODES*HDIM, 0, (size_t)(NROWP-NNODES)*HDIM*sizeof(__bf16), stream);
  hipMemsetAsync(h1b + (size_t)NNODES*HDIM, 0, (size_t)(NROWP-NNODES)*HDIM*sizeof(__bf16), stream);
  cvt_kernel<<<(HDIM*HDIM/4+255)/256, 256, 0, stream>>>(W_gat, wgb, HDIM*HDIM/4);
  cvt_kernel<<<(3*HDIM*HDIM/4+255)/256, 256, 0, stream>>>(W_ih, wihb, 3*HDIM*HDIM/4);
  cvt_kernel<<<(3*HDIM*HDIM/4+255)/256, 256, 0, stream>>>(W_hh, whhb, 3*HDIM*HDIM/4);
  cvt_kernel<<<(ODIM*HDIM/4+255)/256, 256, 0, stream>>>(lin_W, lwb, ODIM*HDIM/4);

  const int RB128 = NROWP/128;            // 157
  const int RB64  = (NNODES+63)/64;       // 313
  __bf16* hc = h0b;
  __bf16* hn = h1b;
  for (int t=0; t<TSTEPS; t++){
    mfma_gemm_nt<<<dim3(RB128, HDIM/64), 256, 0, stream>>>(hc, wgb, nullptr, xpb, nullptr, NNODES, HDIM);
    alpha_kernel<<<(NNODES+3)/4, 256, 0, stream>>>(xpb, att_src, att_dst, as_, ad_);
    gat_aggregate_kernel<<<NNODES, 256, 0, stream>>>(xpb, as_, ad_, rowptr, ssrc, gat_bias, msgb);
    gru_mfma_kernel<<<dim3(RB64, HDIM/64), 256, 0, stream>>>(msgb, hc, hn, wihb, whhb, b_ih, b_hh);
    __bf16* tmp = hc; hc = hn; hn = tmp;
  }
  mfma_gemm_nt<<<dim3(RB128, ODIM/64), 256, 0, stream>>>(hc, lwb, lin_b, nullptr, out, NNODES, ODIM);
}

// Round 3
// 496.645 us; speedup vs baseline: 2.5516x; 1.5113x over previous
//
#include <hip/hip_runtime.h>
#include <math.h>

#define NNODES 20000
#define NROWP  20096   // padded to multiple of 128
#define NEDGES 320000
#define HDIM   256
#define ODIM   128
#define TSTEPS 3
#define KCAT   512     // [msg | h] concatenated K

typedef __bf16 bf16x8 __attribute__((ext_vector_type(8)));
typedef __bf16 bf16x4 __attribute__((ext_vector_type(4)));
typedef float  f32x4  __attribute__((ext_vector_type(4)));

__device__ __forceinline__ float sigmoidf_(float x){ return 1.0f/(1.0f+expf(-x)); }

// async global->LDS 16B: per-lane global addr, wave-uniform LDS base (+lane*16 implicit)
__device__ __forceinline__ void load_lds16(const void* g, void* l){
  __builtin_amdgcn_global_load_lds((const __attribute__((address_space(1))) void*)g,
                                   (__attribute__((address_space(3))) void*)l, 16, 0, 0);
}

// ---------------- converts / prep ----------------
__global__ void cvt_kernel(const float* __restrict__ src, __bf16* __restrict__ dst, int n4){
  int i = blockIdx.x*blockDim.x + threadIdx.x;
  if (i < n4){
    float4 v = ((const float4*)src)[i];
    bf16x4 o; o[0]=(__bf16)v.x; o[1]=(__bf16)v.y; o[2]=(__bf16)v.z; o[3]=(__bf16)v.w;
    ((bf16x4*)dst)[i] = o;
  }
}

// x_clique fp32 [N,256] -> Acat h-slot (cols 256..511 of stride-512 buffer)
__global__ void cvt_h_kernel(const float* __restrict__ src, __bf16* __restrict__ Acat){
  int i = blockIdx.x*blockDim.x + threadIdx.x;   // over NNODES*64
  if (i >= NNODES*64) return;
  int row = i>>6, c = (i&63)<<2;
  float4 v = *(const float4*)&src[(size_t)row*HDIM + c];
  bf16x4 o; o[0]=(__bf16)v.x; o[1]=(__bf16)v.y; o[2]=(__bf16)v.z; o[3]=(__bf16)v.w;
  *(bf16x4*)&Acat[(size_t)row*KCAT + 256 + c] = o;
}

// Bfused[1024][512]: gate-major rows (g*256+c). r,z: [Wih|Whh]; nx: [Wih_n|0]; nh: [0|Whh_n]
__global__ void prep_bf_kernel(const float* __restrict__ Wih, const float* __restrict__ Whh,
                               __bf16* __restrict__ Bf){
  int i = blockIdx.x*blockDim.x + threadIdx.x;   // over 1024*128
  if (i >= 1024*128) return;
  int row = i>>7, kc = (i&127)<<2;
  int gate = row>>8, c = row&255;
  float4 v = make_float4(0,0,0,0);
  if (gate==0 || gate==1){
    v = (kc<256) ? *(const float4*)&Wih[(size_t)(gate*256+c)*HDIM + kc]
                 : *(const float4*)&Whh[(size_t)(gate*256+c)*HDIM + kc-256];
  } else if (gate==2){
    if (kc<256) v = *(const float4*)&Wih[(size_t)(512+c)*HDIM + kc];
  } else {
    if (kc>=256) v = *(const float4*)&Whh[(size_t)(512+c)*HDIM + kc-256];
  }
  bf16x4 o; o[0]=(__bf16)v.x; o[1]=(__bf16)v.y; o[2]=(__bf16)v.z; o[3]=(__bf16)v.w;
  *(bf16x4*)&Bf[(size_t)row*KCAT + kc] = o;
}

// ---------------- CSR build ----------------
__global__ void hist_kernel(const int* __restrict__ dst, int* __restrict__ deg){
  int e = blockIdx.x*blockDim.x + threadIdx.x;
  if (e < NEDGES) atomicAdd(&deg[dst[e]], 1);
}

__global__ void scan_kernel(const int* __restrict__ deg, int* __restrict__ rowptr){
  __shared__ int sdata[1024];
  __shared__ int s_carry;
  int tx = threadIdx.x;
  if (tx==0) s_carry = 0;
  __syncthreads();
  for (int base=0; base<NNODES; base+=1024){
    int i = base+tx;
    int v = (i<NNODES)? deg[i] : 0;
    sdata[tx]=v; __syncthreads();
    #pragma unroll
    for (int off=1; off<1024; off<<=1){
      int t = (tx>=off)? sdata[tx-off] : 0;
      __syncthreads();
      sdata[tx] += t;
      __syncthreads();
    }
    if (i<NNODES) rowptr[i] = s_carry + sdata[tx] - v;
    int tot = sdata[1023];
    __syncthreads();
    if (tx==0) s_carry += tot;
    __syncthreads();
  }
  if (tx==0) rowptr[NNODES] = s_carry;
}

__global__ void scatter_kernel(const int* __restrict__ src, const int* __restrict__ dst,
                               const int* __restrict__ rowptr, int* __restrict__ fill,
                               int* __restrict__ ssrc){
  int e = blockIdx.x*blockDim.x + threadIdx.x;
  if (e < NEDGES){
    int d = dst[e];
    int pos = rowptr[d] + atomicAdd(&fill[d], 1);
    ssrc[pos] = src[e];
  }
}

// ---------------- LDS-staged MFMA GEMM: C[M,Nc] = A[M,K=256] @ B[Nc,256]^T ----------------
// 128 x NT tile, BK=32, global_load_lds staging, 4 waves (64 x NT/2 each)
template<int NT, bool F32OUT>
__global__ __launch_bounds__(256)
void mfma_gemm_lds(const __bf16* __restrict__ A, int lda,
                   const __bf16* __restrict__ B,
                   const float* __restrict__ bias,
                   __bf16* __restrict__ Cb, float* __restrict__ Cf,
                   int ldc, int Mreal){
  constexpr int JF = NT/32;
  __shared__ __bf16 As[128*32];
  __shared__ __bf16 Bs[NT*32];
  int tx = threadIdx.x, lane = tx&63, w = tx>>6;
  int r0 = blockIdx.x*128, c0 = blockIdx.y*NT;
  f32x4 acc[4][JF] = {};
  for (int k0=0; k0<HDIM; k0+=32){
    #pragma unroll
    for (int q=0;q<2;q++){
      int c = q*256 + w*64 + lane;
      load_lds16(A + (size_t)(r0 + (c>>2))*lda + k0 + ((c&3)<<3),
                 (char*)As + (q*256 + w*64)*16);
    }
    #pragma unroll
    for (int q=0;q<NT/64;q++){
      int c = q*256 + w*64 + lane;
      load_lds16(B + (size_t)(c0 + (c>>2))*HDIM + k0 + ((c&3)<<3),
                 (char*)Bs + (q*256 + w*64)*16);
    }
    __syncthreads();
    int rbase = (w&1)*64, cbase = (w>>1)*(NT/2);
    bf16x8 a[4], b[JF];
    #pragma unroll
    for (int i=0;i<4;i++)
      a[i] = *(const bf16x8*)&As[(rbase + i*16 + (lane&15))*32 + ((lane>>4)<<3)];
    #pragma unroll
    for (int j=0;j<JF;j++)
      b[j] = *(const bf16x8*)&Bs[(cbase + j*16 + (lane&15))*32 + ((lane>>4)<<3)];
    #pragma unroll
    for (int i=0;i<4;i++)
      #pragma unroll
      for (int j=0;j<JF;j++)
        acc[i][j] = __builtin_amdgcn_mfma_f32_16x16x32_bf16(a[i], b[j], acc[i][j], 0,0,0);
    __syncthreads();
  }
  int rbase = r0 + (w&1)*64, cbase = c0 + (w>>1)*(NT/2);
  #pragma unroll
  for (int i=0;i<4;i++){
    #pragma unroll
    for (int j=0;j<JF;j++){
      int gc = cbase + j*16 + (lane&15);
      float bv = F32OUT ? bias[gc] : 0.f;
      #pragma unroll
      for (int r=0;r<4;r++){
        int gr = rbase + i*16 + ((lane>>4)<<2) + r;
        if (gr >= Mreal) continue;
        float v = acc[i][j][r] + bv;
        if (F32OUT) Cf[(size_t)gr*ldc + gc] = v;
        else        Cb[(size_t)gr*ldc + gc] = (__bf16)v;
      }
    }
  }
}

// ---------------- attention logits ----------------
__global__ void alpha_kernel(const __bf16* __restrict__ xpb, const float* __restrict__ att_src,
                             const float* __restrict__ att_dst,
                             float* __restrict__ as_, float* __restrict__ ad_){
  int node = blockIdx.x*4 + (threadIdx.x>>6);
  int lane = threadIdx.x & 63;
  if (node >= NNODES) return;
  bf16x4 v4 = *(const bf16x4*)&xpb[(size_t)node*HDIM + lane*4];
  float4 a = *(const float4*)&att_src[lane*4];
  float4 b = *(const float4*)&att_dst[lane*4];
  float v0=(float)v4[0], v1=(float)v4[1], v2=(float)v4[2], v3=(float)v4[3];
  float ps = v0*a.x + v1*a.y + v2*a.z + v3*a.w;
  float pd = v0*b.x + v1*b.y + v2*b.z + v3*b.w;
  for (int off=32; off; off>>=1){ ps += __shfl_down(ps,off); pd += __shfl_down(pd,off); }
  if (lane==0){ as_[node]=ps; ad_[node]=pd; }
}

// ---------------- GAT softmax+aggregate: ONE WAVE PER NODE ----------------
__global__ __launch_bounds__(256)
void gat_aggregate_kernel(const __bf16* __restrict__ xpb, const float* __restrict__ as_,
                          const float* __restrict__ ad_, const int* __restrict__ rowptr,
                          const int* __restrict__ ssrc, const float* __restrict__ gat_bias,
                          __bf16* __restrict__ Acat){
  int node = blockIdx.x*4 + (threadIdx.x>>6);
  int lane = threadIdx.x & 63;
  if (node >= NNODES) return;
  int beg = rowptr[node], end = rowptr[node+1];
  float adv = ad_[node];

  float mx = -INFINITY;
  for (int e=beg+lane; e<end; e+=64){
    float a = as_[ssrc[e]] + adv;
    a = (a>0.f)? a : 0.01f*a;
    mx = fmaxf(mx, a);
  }
  for (int off=32; off; off>>=1) mx = fmaxf(mx, __shfl_down(mx,off));
  mx = __shfl(mx, 0);

  float sm = 0.f;
  for (int e=beg+lane; e<end; e+=64){
    float a = as_[ssrc[e]] + adv;
    a = (a>0.f)? a : 0.01f*a;
    sm += expf(a - mx);
  }
  for (int off=32; off; off>>=1) sm += __shfl_down(sm,off);
  sm = __shfl(sm, 0);
  float scale = 1.0f/fmaxf(sm, 1e-16f);

  float4 acc = make_float4(0,0,0,0);
  for (int cb=beg; cb<end; cb+=64){
    int n = end-cb; if (n>64) n=64;
    int sreg = 0; float creg = 0.f;
    if (lane < n){
      sreg = ssrc[cb+lane];
      float a = as_[sreg] + adv;
      a = (a>0.f)? a : 0.01f*a;
      creg = expf(a - mx)*scale;
    }
    for (int j=0;j<n;j++){
      float coef = __shfl(creg, j);
      int row    = __shfl(sreg, j);
      bf16x4 v = *(const bf16x4*)&xpb[(size_t)row*HDIM + lane*4];
      acc.x += coef*(float)v[0]; acc.y += coef*(float)v[1];
      acc.z += coef*(float)v[2]; acc.w += coef*(float)v[3];
    }
  }
  float4 bv = *(const float4*)&gat_bias[lane*4];
  float o0=acc.x+bv.x, o1=acc.y+bv.y, o2=acc.z+bv.z, o3=acc.w+bv.w;
  bf16x4 ov;
  ov[0]=(__bf16)((o0>0.f)?o0:(expf(o0)-1.f));
  ov[1]=(__bf16)((o1>0.f)?o1:(expf(o1)-1.f));
  ov[2]=(__bf16)((o2>0.f)?o2:(expf(o2)-1.f));
  ov[3]=(__bf16)((o3>0.f)?o3:(expf(o3)-1.f));
  *(bf16x4*)&Acat[(size_t)node*KCAT + lane*4] = ov;   // msg slot (cols 0..255)
}

// ---------------- fused GRU: C[M, 4 gates x 64 cols] = Acat @ Bfused^T, GRU epilogue ----------------
// block: 128 rows x 64 real cols (256 B-rows), BK=32, K=512. wave: 64 rows x 32 cols x 4 gates.
__global__ __launch_bounds__(256,2)
void gru_mfma_kernel(const __bf16* __restrict__ Acat, __bf16* __restrict__ AcatN,
                     const __bf16* __restrict__ Bf,
                     const float* __restrict__ bih, const float* __restrict__ bhh){
  __shared__ __bf16 As[128*32];
  __shared__ __bf16 Bs[256*32];
  int tx = threadIdx.x, lane = tx&63, w = tx>>6;
  int r0 = blockIdx.x*128, c0 = blockIdx.y*64;
  f32x4 acc[4][4][2] = {};   // [gate][rowfrag][colfrag]
  for (int k0=0; k0<KCAT; k0+=32){
    #pragma unroll
    for (int q=0;q<2;q++){
      int c = q*256 + w*64 + lane;
      load_lds16(Acat + (size_t)(r0 + (c>>2))*KCAT + k0 + ((c&3)<<3),
                 (char*)As + (q*256 + w*64)*16);
    }
    #pragma unroll
    for (int q=0;q<4;q++){
      int c = q*256 + w*64 + lane;
      int brow = c>>2;                         // 0..255 = gate*64 + col
      int gate = brow>>6, col = brow&63;
      load_lds16(Bf + (size_t)(gate*256 + c0 + col)*KCAT + k0 + ((c&3)<<3),
                 (char*)Bs + (q*256 + w*64)*16);
    }
    __syncthreads();
    int rbase = (w&1)*64, cbase = (w>>1)*32;
    bf16x8 a[4], b[4][2];
    #pragma unroll
    for (int i=0;i<4;i++)
      a[i] = *(const bf16x8*)&As[(rbase + i*16 + (lane&15))*32 + ((lane>>4)<<3)];
    #pragma unroll
    for (int g=0;g<4;g++)
      #pragma unroll
      for (int j=0;j<2;j++)
        b[g][j] = *(const bf16x8*)&Bs[(g*64 + cbase + j*16 + (lane&15))*32 + ((lane>>4)<<3)];
    #pragma unroll
    for (int g=0;g<4;g++)
      #pragma unroll
      for (int i=0;i<4;i++)
        #pragma unroll
        for (int j=0;j<2;j++)
          acc[g][i][j] = __builtin_amdgcn_mfma_f32_16x16x32_bf16(a[i], b[g][j], acc[g][i][j], 0,0,0);
    __syncthreads();
  }
  int rbase = r0 + (w&1)*64, cb = (w>>1)*32;
  #pragma unroll
  for (int i=0;i<4;i++){
    #pragma unroll
    for (int j=0;j<2;j++){
      int gc = c0 + cb + j*16 + (lane&15);
      float br_ = bih[gc]     + bhh[gc];
      float bz_ = bih[256+gc] + bhh[256+gc];
      float bnx = bih[512+gc];
      float bnh = bhh[512+gc];
      #pragma unroll
      for (int r=0;r<4;r++){
        int gr = rbase + i*16 + ((lane>>4)<<2) + r;
        if (gr >= NNODES) continue;
        float hold = (float)Acat[(size_t)gr*KCAT + 256 + gc];
        float rr = sigmoidf_(acc[0][i][j][r] + br_);
        float zz = sigmoidf_(acc[1][i][j][r] + bz_);
        float nn = tanhf(acc[2][i][j][r] + bnx + rr*(acc[3][i][j][r] + bnh));
        AcatN[(size_t)gr*KCAT + 256 + gc] = (__bf16)((1.f-zz)*nn + zz*hold);
      }
    }
  }
}

// ---------------- launch ----------------
extern "C" void kernel_launch(void* const* d_in, const int* in_sizes, int n_in,
                              void* d_out, int out_size, void* d_ws, size_t ws_size,
                              hipStream_t stream) {
  const float* x_clique = (const float*)d_in[0];
  const float* W_gat    = (const float*)d_in[1];
  const float* att_src  = (const float*)d_in[2];
  const float* att_dst  = (const float*)d_in[3];
  const float* gat_bias = (const float*)d_in[4];
  const float* W_ih     = (const float*)d_in[5];
  const float* W_hh     = (const float*)d_in[6];
  const float* b_ih     = (const float*)d_in[7];
  const float* b_hh     = (const float*)d_in[8];
  const float* lin_W    = (const float*)d_in[9];
  const float* lin_b    = (const float*)d_in[10];
  const int*   eidx     = (const int*)d_in[14];
  float* out = (float*)d_out;

  const int* src = eidx;
  const int* dst = eidx + NEDGES;

  const size_t ACAT = (size_t)NROWP*KCAT;
  __bf16* AcA  = (__bf16*)d_ws;
  __bf16* AcB  = AcA + ACAT;
  __bf16* xpb  = AcB + ACAT;                        // [NROWP][256]
  __bf16* Bf   = xpb + (size_t)NROWP*HDIM;          // [1024][512]
  __bf16* wgb  = Bf  + (size_t)1024*KCAT;           // [256][256]
  __bf16* lwb  = wgb + (size_t)HDIM*HDIM;           // [128][256]
  float* as_   = (float*)(lwb + (size_t)ODIM*HDIM);
  float* ad_   = as_ + NNODES;
  int* deg     = (int*)(ad_ + NNODES);
  int* fill    = deg + NNODES;
  int* rowptr  = fill + NNODES;
  int* ssrc    = rowptr + (NNODES+1);

  // CSR build
  hipMemsetAsync(deg,  0, NNODES*sizeof(int), stream);
  hipMemsetAsync(fill, 0, NNODES*sizeof(int), stream);
  hist_kernel<<<(NEDGES+255)/256, 256, 0, stream>>>(dst, deg);
  scan_kernel<<<1, 1024, 0, stream>>>(deg, rowptr);
  scatter_kernel<<<(NEDGES+255)/256, 256, 0, stream>>>(src, dst, rowptr, fill, ssrc);

  // weight preps
  cvt_h_kernel<<<(NNODES*64+255)/256, 256, 0, stream>>>(x_clique, AcA);
  prep_bf_kernel<<<(1024*128+255)/256, 256, 0, stream>>>(W_ih, W_hh, Bf);
  cvt_kernel<<<(HDIM*HDIM/4+255)/256, 256, 0, stream>>>(W_gat, wgb, HDIM*HDIM/4);
  cvt_kernel<<<(ODIM*HDIM/4+255)/256, 256, 0, stream>>>(lin_W, lwb, ODIM*HDIM/4);

  const int RB = NROWP/128;   // 157
  __bf16* Ac = AcA;
  __bf16* An = AcB;
  for (int t=0; t<TSTEPS; t++){
    mfma_gemm_lds<64,false><<<dim3(RB, HDIM/64), 256, 0, stream>>>(
        Ac + 256, KCAT, wgb, nullptr, xpb, nullptr, HDIM, NNODES);
    alpha_kernel<<<(NNODES+3)/4, 256, 0, stream>>>(xpb, att_src, att_dst, as_, ad_);
    gat_aggregate_kernel<<<(NNODES+3)/4, 256, 0, stream>>>(xpb, as_, ad_, rowptr, ssrc, gat_bias, Ac);
    gru_mfma_kernel<<<dim3(RB, 4), 256, 0, stream>>>(Ac, An, Bf, b_ih, b_hh);
    __bf16* tmp = Ac; Ac = An; An = tmp;
  }
  mfma_gemm_lds<128,true><<<dim3(RB, 1), 256, 0, stream>>>(
      Ac + 256, KCAT, lwb, lin_b, nullptr, out, ODIM, NNODES);
}

// Round 4
// 440.696 us; speedup vs baseline: 2.8755x; 1.1270x over previous
//
#include <hip/hip_runtime.h>
#include <math.h>

#define NNODES 20000
#define NROWP  20096   // padded to multiple of 128
#define NEDGES 320000
#define HDIM   256
#define ODIM   128
#define TSTEPS 3
#define KCAT   512     // [msg | h] concatenated K

typedef __bf16 bf16x8 __attribute__((ext_vector_type(8)));
typedef __bf16 bf16x4 __attribute__((ext_vector_type(4)));
typedef float  f32x4  __attribute__((ext_vector_type(4)));

#define LOG2E 1.44269504f
__device__ __forceinline__ float fexp2_(float x){ return __builtin_amdgcn_exp2f(x); }
__device__ __forceinline__ float frcp_(float x){ return __builtin_amdgcn_rcpf(x); }
__device__ __forceinline__ float fsig_(float x){ return frcp_(1.f + fexp2_(-LOG2E*x)); }
__device__ __forceinline__ float ftanh_(float x){ float t = fexp2_(2.f*LOG2E*x); return 1.f - 2.f*frcp_(t+1.f); }
__device__ __forceinline__ float felu_(float x){ return (x>0.f)? x : (fexp2_(LOG2E*x)-1.f); }

// async global->LDS 16B: per-lane global addr, wave-uniform LDS base (+lane*16 implicit)
__device__ __forceinline__ void load_lds16(const void* g, void* l){
  __builtin_amdgcn_global_load_lds((const __attribute__((address_space(1))) void*)g,
                                   (__attribute__((address_space(3))) void*)l, 16, 0, 0);
}

// Swizzled LDS fragment read: tile stored as rows x 4 granules(16B),
// granule (row,kg) lives at slot row*4 + (kg ^ ((row>>1)&3))  -> conflict-free b128.
__device__ __forceinline__ bf16x8 lds_frag(const __bf16* Ls, int rowbase, int lane){
  int row = rowbase + (lane&15);
  int slot = (row<<2) + ((lane>>4) ^ ((row>>1)&3));
  return *(const bf16x8*)&Ls[slot<<3];
}

// ---------------- converts / prep ----------------
__global__ void cvt_kernel(const float* __restrict__ src, __bf16* __restrict__ dst, int n4){
  int i = blockIdx.x*blockDim.x + threadIdx.x;
  if (i < n4){
    float4 v = ((const float4*)src)[i];
    bf16x4 o; o[0]=(__bf16)v.x; o[1]=(__bf16)v.y; o[2]=(__bf16)v.z; o[3]=(__bf16)v.w;
    ((bf16x4*)dst)[i] = o;
  }
}

__global__ void cvt_h_kernel(const float* __restrict__ src, __bf16* __restrict__ Acat){
  int i = blockIdx.x*blockDim.x + threadIdx.x;   // over NNODES*64
  if (i >= NNODES*64) return;
  int row = i>>6, c = (i&63)<<2;
  float4 v = *(const float4*)&src[(size_t)row*HDIM + c];
  bf16x4 o; o[0]=(__bf16)v.x; o[1]=(__bf16)v.y; o[2]=(__bf16)v.z; o[3]=(__bf16)v.w;
  *(bf16x4*)&Acat[(size_t)row*KCAT + 256 + c] = o;
}

// Bfused[1024][512]: gate-major rows (g*256+c). r,z: [Wih|Whh]; nx: [Wih_n|0]; nh: [0|Whh_n]
__global__ void prep_bf_kernel(const float* __restrict__ Wih, const float* __restrict__ Whh,
                               __bf16* __restrict__ Bf){
  int i = blockIdx.x*blockDim.x + threadIdx.x;   // over 1024*128
  if (i >= 1024*128) return;
  int row = i>>7, kc = (i&127)<<2;
  int gate = row>>8, c = row&255;
  float4 v = make_float4(0,0,0,0);
  if (gate==0 || gate==1){
    v = (kc<256) ? *(const float4*)&Wih[(size_t)(gate*256+c)*HDIM + kc]
                 : *(const float4*)&Whh[(size_t)(gate*256+c)*HDIM + kc-256];
  } else if (gate==2){
    if (kc<256) v = *(const float4*)&Wih[(size_t)(512+c)*HDIM + kc];
  } else {
    if (kc>=256) v = *(const float4*)&Whh[(size_t)(512+c)*HDIM + kc-256];
  }
  bf16x4 o; o[0]=(__bf16)v.x; o[1]=(__bf16)v.y; o[2]=(__bf16)v.z; o[3]=(__bf16)v.w;
  *(bf16x4*)&Bf[(size_t)row*KCAT + kc] = o;
}

// ---------------- CSR build ----------------
__global__ void hist_kernel(const int* __restrict__ dst, int* __restrict__ deg){
  int e = blockIdx.x*blockDim.x + threadIdx.x;
  if (e < NEDGES) atomicAdd(&deg[dst[e]], 1);
}

__global__ void scan_kernel(const int* __restrict__ deg, int* __restrict__ rowptr){
  __shared__ int sdata[1024];
  __shared__ int s_carry;
  int tx = threadIdx.x;
  if (tx==0) s_carry = 0;
  __syncthreads();
  for (int base=0; base<NNODES; base+=1024){
    int i = base+tx;
    int v = (i<NNODES)? deg[i] : 0;
    sdata[tx]=v; __syncthreads();
    #pragma unroll
    for (int off=1; off<1024; off<<=1){
      int t = (tx>=off)? sdata[tx-off] : 0;
      __syncthreads();
      sdata[tx] += t;
      __syncthreads();
    }
    if (i<NNODES) rowptr[i] = s_carry + sdata[tx] - v;
    int tot = sdata[1023];
    __syncthreads();
    if (tx==0) s_carry += tot;
    __syncthreads();
  }
  if (tx==0) rowptr[NNODES] = s_carry;
}

__global__ void scatter_kernel(const int* __restrict__ src, const int* __restrict__ dst,
                               const int* __restrict__ rowptr, int* __restrict__ fill,
                               int* __restrict__ ssrc){
  int e = blockIdx.x*blockDim.x + threadIdx.x;
  if (e < NEDGES){
    int d = dst[e];
    int pos = rowptr[d] + atomicAdd(&fill[d], 1);
    ssrc[pos] = src[e];
  }
}

// ---------------- LDS-staged MFMA GEMM (swizzled): C[M,Nc]=A[M,256]@B[Nc,256]^T ----------------
template<int NT, bool F32OUT>
__global__ __launch_bounds__(256)
void mfma_gemm_lds(const __bf16* __restrict__ A, int lda,
                   const __bf16* __restrict__ B,
                   const float* __restrict__ bias,
                   __bf16* __restrict__ Cb, float* __restrict__ Cf,
                   int ldc, int Mreal){
  constexpr int JF = NT/32;
  __shared__ __bf16 As[128*32];
  __shared__ __bf16 Bs[NT*32];
  int tx = threadIdx.x, lane = tx&63, w = tx>>6;
  int r0 = blockIdx.x*128, c0 = blockIdx.y*NT;
  f32x4 acc[4][JF] = {};
  for (int k0=0; k0<HDIM; k0+=32){
    #pragma unroll
    for (int q=0;q<2;q++){
      int c = q*256 + w*64 + lane;
      int row = c>>2, kg = (c&3) ^ ((row>>1)&3);
      load_lds16(A + (size_t)(r0 + row)*lda + k0 + (kg<<3),
                 (char*)As + (q*256 + w*64)*16);
    }
    #pragma unroll
    for (int q=0;q<NT/64;q++){
      int c = q*256 + w*64 + lane;
      int row = c>>2, kg = (c&3) ^ ((row>>1)&3);
      load_lds16(B + (size_t)(c0 + row)*HDIM + k0 + (kg<<3),
                 (char*)Bs + (q*256 + w*64)*16);
    }
    __syncthreads();
    int rbase = (w&1)*64, cbase = (w>>1)*(NT/2);
    bf16x8 a[4], b[JF];
    #pragma unroll
    for (int i=0;i<4;i++) a[i] = lds_frag(As, rbase + i*16, lane);
    #pragma unroll
    for (int j=0;j<JF;j++) b[j] = lds_frag(Bs, cbase + j*16, lane);
    #pragma unroll
    for (int i=0;i<4;i++)
      #pragma unroll
      for (int j=0;j<JF;j++)
        acc[i][j] = __builtin_amdgcn_mfma_f32_16x16x32_bf16(a[i], b[j], acc[i][j], 0,0,0);
    __syncthreads();
  }
  int rbase = r0 + (w&1)*64, cbase = c0 + (w>>1)*(NT/2);
  #pragma unroll
  for (int i=0;i<4;i++){
    #pragma unroll
    for (int j=0;j<JF;j++){
      int gc = cbase + j*16 + (lane&15);
      float bv = F32OUT ? bias[gc] : 0.f;
      #pragma unroll
      for (int r=0;r<4;r++){
        int gr = rbase + i*16 + ((lane>>4)<<2) + r;
        if (gr >= Mreal) continue;
        float v = acc[i][j][r] + bv;
        if (F32OUT) Cf[(size_t)gr*ldc + gc] = v;
        else        Cb[(size_t)gr*ldc + gc] = (__bf16)v;
      }
    }
  }
}

// ---------------- attention logits ----------------
__global__ void alpha_kernel(const __bf16* __restrict__ xpb, const float* __restrict__ att_src,
                             const float* __restrict__ att_dst,
                             float* __restrict__ as_, float* __restrict__ ad_){
  int node = blockIdx.x*4 + (threadIdx.x>>6);
  int lane = threadIdx.x & 63;
  if (node >= NNODES) return;
  bf16x4 v4 = *(const bf16x4*)&xpb[(size_t)node*HDIM + lane*4];
  float4 a = *(const float4*)&att_src[lane*4];
  float4 b = *(const float4*)&att_dst[lane*4];
  float v0=(float)v4[0], v1=(float)v4[1], v2=(float)v4[2], v3=(float)v4[3];
  float ps = v0*a.x + v1*a.y + v2*a.z + v3*a.w;
  float pd = v0*b.x + v1*b.y + v2*b.z + v3*b.w;
  for (int off=32; off; off>>=1){ ps += __shfl_down(ps,off); pd += __shfl_down(pd,off); }
  if (lane==0){ as_[node]=ps; ad_[node]=pd; }
}

// ---------------- GAT softmax+aggregate: one wave/node, 32 lanes/row, 2 edges/load ----------------
__global__ __launch_bounds__(256)
void gat_aggregate_kernel(const __bf16* __restrict__ xpb, const float* __restrict__ as_,
                          const float* __restrict__ ad_, const int* __restrict__ rowptr,
                          const int* __restrict__ ssrc, const float* __restrict__ gat_bias,
                          __bf16* __restrict__ Acat){
  int node = blockIdx.x*4 + (threadIdx.x>>6);
  int lane = threadIdx.x & 63;
  if (node >= NNODES) return;
  int beg = rowptr[node], end = rowptr[node+1];
  int deg = end - beg;
  float adv = ad_[node];
  int half = lane>>5, col = lane&31;

  float acc[8] = {0,0,0,0,0,0,0,0};

  if (deg <= 64){
    // single pass over logits: one as_ gather total
    float a = -INFINITY; int sreg = 0;
    if (lane < deg){
      sreg = ssrc[beg+lane];
      a = as_[sreg] + adv;
      a = (a>0.f)? a : 0.01f*a;
    }
    float mx = a;
    #pragma unroll
    for (int off=32; off; off>>=1) mx = fmaxf(mx, __shfl_xor(mx,off));
    float e = (lane<deg)? fexp2_(LOG2E*(a-mx)) : 0.f;
    float sm = e;
    #pragma unroll
    for (int off=32; off; off>>=1) sm += __shfl_xor(sm,off);
    float creg = e*frcp_(fmaxf(sm,1e-16f));

    int j = 0;
    for (; j+8<=deg; j+=8){
      float c0=__shfl(creg,j+0+half), c1=__shfl(creg,j+2+half),
            c2=__shfl(creg,j+4+half), c3=__shfl(creg,j+6+half);
      int   r0=__shfl(sreg,j+0+half), r1=__shfl(sreg,j+2+half),
            r2=__shfl(sreg,j+4+half), r3=__shfl(sreg,j+6+half);
      bf16x8 v0 = *(const bf16x8*)&xpb[(size_t)r0*HDIM + col*8];
      bf16x8 v1 = *(const bf16x8*)&xpb[(size_t)r1*HDIM + col*8];
      bf16x8 v2 = *(const bf16x8*)&xpb[(size_t)r2*HDIM + col*8];
      bf16x8 v3 = *(const bf16x8*)&xpb[(size_t)r3*HDIM + col*8];
      #pragma unroll
      for (int t=0;t<8;t++)
        acc[t] += c0*(float)v0[t] + c1*(float)v1[t] + c2*(float)v2[t] + c3*(float)v3[t];
    }
    for (; j<deg; j+=2){
      int jj = j + half;
      float cf = __shfl(creg, jj);
      int   rw = __shfl(sreg, jj);
      if (jj < deg){
        bf16x8 v = *(const bf16x8*)&xpb[(size_t)rw*HDIM + col*8];
        #pragma unroll
        for (int t=0;t<8;t++) acc[t] += cf*(float)v[t];
      }
    }
  } else {
    // general path (rare): 3-pass
    float mx = -INFINITY;
    for (int e=beg+lane; e<end; e+=64){
      float a = as_[ssrc[e]] + adv;
      a = (a>0.f)? a : 0.01f*a;
      mx = fmaxf(mx, a);
    }
    #pragma unroll
    for (int off=32; off; off>>=1) mx = fmaxf(mx, __shfl_xor(mx,off));
    float sm = 0.f;
    for (int e=beg+lane; e<end; e+=64){
      float a = as_[ssrc[e]] + adv;
      a = (a>0.f)? a : 0.01f*a;
      sm += fexp2_(LOG2E*(a-mx));
    }
    #pragma unroll
    for (int off=32; off; off>>=1) sm += __shfl_xor(sm,off);
    float rsc = frcp_(fmaxf(sm,1e-16f));
    for (int j=0; j<deg; j+=2){
      int jj = j + half;
      if (jj < deg){
        int rw = ssrc[beg+jj];
        float a = as_[rw] + adv;
        a = (a>0.f)? a : 0.01f*a;
        float cf = fexp2_(LOG2E*(a-mx))*rsc;
        bf16x8 v = *(const bf16x8*)&xpb[(size_t)rw*HDIM + col*8];
        #pragma unroll
        for (int t=0;t<8;t++) acc[t] += cf*(float)v[t];
      }
    }
  }

  #pragma unroll
  for (int t=0;t<8;t++) acc[t] += __shfl_down(acc[t], 32);
  if (half==0){
    float4 b0 = *(const float4*)&gat_bias[col*8];
    float4 b1 = *(const float4*)&gat_bias[col*8+4];
    float bb[8] = {b0.x,b0.y,b0.z,b0.w,b1.x,b1.y,b1.z,b1.w};
    bf16x8 ov;
    #pragma unroll
    for (int t=0;t<8;t++) ov[t] = (__bf16)felu_(acc[t]+bb[t]);
    *(bf16x8*)&Acat[(size_t)node*KCAT + col*8] = ov;   // msg slot
  }
}

// ---------------- fused GRU: Acat @ Bfused^T + GRU epilogue (swizzled LDS) ----------------
__global__ __launch_bounds__(256,2)
void gru_mfma_kernel(const __bf16* __restrict__ Acat, __bf16* __restrict__ AcatN,
                     const __bf16* __restrict__ Bf,
                     const float* __restrict__ bih, const float* __restrict__ bhh){
  __shared__ __bf16 As[128*32];
  __shared__ __bf16 Bs[256*32];
  int tx = threadIdx.x, lane = tx&63, w = tx>>6;
  int r0 = blockIdx.x*128, c0 = blockIdx.y*64;
  f32x4 acc[4][4][2] = {};   // [gate][rowfrag][colfrag]
  for (int k0=0; k0<KCAT; k0+=32){
    #pragma unroll
    for (int q=0;q<2;q++){
      int c = q*256 + w*64 + lane;
      int row = c>>2, kg = (c&3) ^ ((row>>1)&3);
      load_lds16(Acat + (size_t)(r0 + row)*KCAT + k0 + (kg<<3),
                 (char*)As + (q*256 + w*64)*16);
    }
    #pragma unroll
    for (int q=0;q<4;q++){
      int c = q*256 + w*64 + lane;
      int row = c>>2, kg = (c&3) ^ ((row>>1)&3);
      int gate = row>>6, colr = row&63;
      load_lds16(Bf + (size_t)(gate*256 + c0 + colr)*KCAT + k0 + (kg<<3),
                 (char*)Bs + (q*256 + w*64)*16);
    }
    __syncthreads();
    int rbase = (w&1)*64, cbase = (w>>1)*32;
    bf16x8 a[4], b[4][2];
    #pragma unroll
    for (int i=0;i<4;i++) a[i] = lds_frag(As, rbase + i*16, lane);
    #pragma unroll
    for (int g=0;g<4;g++)
      #pragma unroll
      for (int j=0;j<2;j++) b[g][j] = lds_frag(Bs, g*64 + cbase + j*16, lane);
    #pragma unroll
    for (int g=0;g<4;g++)
      #pragma unroll
      for (int i=0;i<4;i++)
        #pragma unroll
        for (int j=0;j<2;j++)
          acc[g][i][j] = __builtin_amdgcn_mfma_f32_16x16x32_bf16(a[i], b[g][j], acc[g][i][j], 0,0,0);
    __syncthreads();
  }
  int rbase = r0 + (w&1)*64, cb = (w>>1)*32;
  #pragma unroll
  for (int i=0;i<4;i++){
    #pragma unroll
    for (int j=0;j<2;j++){
      int gc = c0 + cb + j*16 + (lane&15);
      float br_ = bih[gc]     + bhh[gc];
      float bz_ = bih[256+gc] + bhh[256+gc];
      float bnx = bih[512+gc];
      float bnh = bhh[512+gc];
      #pragma unroll
      for (int r=0;r<4;r++){
        int gr = rbase + i*16 + ((lane>>4)<<2) + r;
        if (gr >= NNODES) continue;
        float hold = (float)Acat[(size_t)gr*KCAT + 256 + gc];
        float rr = fsig_(acc[0][i][j][r] + br_);
        float zz = fsig_(acc[1][i][j][r] + bz_);
        float nn = ftanh_(acc[2][i][j][r] + bnx + rr*(acc[3][i][j][r] + bnh));
        AcatN[(size_t)gr*KCAT + 256 + gc] = (__bf16)((1.f-zz)*nn + zz*hold);
      }
    }
  }
}

// ---------------- launch ----------------
extern "C" void kernel_launch(void* const* d_in, const int* in_sizes, int n_in,
                              void* d_out, int out_size, void* d_ws, size_t ws_size,
                              hipStream_t stream) {
  const float* x_clique = (const float*)d_in[0];
  const float* W_gat    = (const float*)d_in[1];
  const float* att_src  = (const float*)d_in[2];
  const float* att_dst  = (const float*)d_in[3];
  const float* gat_bias = (const float*)d_in[4];
  const float* W_ih     = (const float*)d_in[5];
  const float* W_hh     = (const float*)d_in[6];
  const float* b_ih     = (const float*)d_in[7];
  const float* b_hh     = (const float*)d_in[8];
  const float* lin_W    = (const float*)d_in[9];
  const float* lin_b    = (const float*)d_in[10];
  const int*   eidx     = (const int*)d_in[14];
  float* out = (float*)d_out;

  const int* src = eidx;
  const int* dst = eidx + NEDGES;

  const size_t ACAT = (size_t)NROWP*KCAT;
  __bf16* AcA  = (__bf16*)d_ws;
  __bf16* AcB  = AcA + ACAT;
  __bf16* xpb  = AcB + ACAT;                        // [NROWP][256]
  __bf16* Bf   = xpb + (size_t)NROWP*HDIM;          // [1024][512]
  __bf16* wgb  = Bf  + (size_t)1024*KCAT;           // [256][256]
  __bf16* lwb  = wgb + (size_t)HDIM*HDIM;           // [128][256]
  float* as_   = (float*)(lwb + (size_t)ODIM*HDIM);
  float* ad_   = as_ + NNODES;
  int* deg     = (int*)(ad_ + NNODES);
  int* fill    = deg + NNODES;
  int* rowptr  = fill + NNODES;
  int* ssrc    = rowptr + (NNODES+1);

  // CSR build
  hipMemsetAsync(deg,  0, NNODES*sizeof(int), stream);
  hipMemsetAsync(fill, 0, NNODES*sizeof(int), stream);
  hist_kernel<<<(NEDGES+255)/256, 256, 0, stream>>>(dst, deg);
  scan_kernel<<<1, 1024, 0, stream>>>(deg, rowptr);
  scatter_kernel<<<(NEDGES+255)/256, 256, 0, stream>>>(src, dst, rowptr, fill, ssrc);

  // weight preps
  cvt_h_kernel<<<(NNODES*64+255)/256, 256, 0, stream>>>(x_clique, AcA);
  prep_bf_kernel<<<(1024*128+255)/256, 256, 0, stream>>>(W_ih, W_hh, Bf);
  cvt_kernel<<<(HDIM*HDIM/4+255)/256, 256, 0, stream>>>(W_gat, wgb, HDIM*HDIM/4);
  cvt_kernel<<<(ODIM*HDIM/4+255)/256, 256, 0, stream>>>(lin_W, lwb, ODIM*HDIM/4);

  const int RB = NROWP/128;   // 157
  __bf16* Ac = AcA;
  __bf16* An = AcB;
  for (int t=0; t<TSTEPS; t++){
    mfma_gemm_lds<64,false><<<dim3(RB, HDIM/64), 256, 0, stream>>>(
        Ac + 256, KCAT, wgb, nullptr, xpb, nullptr, HDIM, NNODES);
    alpha_kernel<<<(NNODES+3)/4, 256, 0, stream>>>(xpb, att_src, att_dst, as_, ad_);
    gat_aggregate_kernel<<<(NNODES+3)/4, 256, 0, stream>>>(xpb, as_, ad_, rowptr, ssrc, gat_bias, Ac);
    gru_mfma_kernel<<<dim3(RB, 4), 256, 0, stream>>>(Ac, An, Bf, b_ih, b_hh);
    __bf16* tmp = Ac; Ac = An; An = tmp;
  }
  mfma_gemm_lds<128,true><<<dim3(RB, 1), 256, 0, stream>>>(
      Ac + 256, KCAT, lwb, lin_b, nullptr, out, ODIM, NNODES);
}

// Round 5
// 417.391 us; speedup vs baseline: 3.0361x; 1.0558x over previous
//
#include <hip/hip_runtime.h>
#include <math.h>

#define NNODES 20000
#define NROWP  20096   // padded to multiple of 128
#define NEDGES 320000
#define HDIM   256
#define ODIM   128
#define TSTEPS 3
#define KCAT   512     // [msg | h] concatenated K

typedef __bf16 bf16x8 __attribute__((ext_vector_type(8)));
typedef __bf16 bf16x4 __attribute__((ext_vector_type(4)));
typedef float  f32x4  __attribute__((ext_vector_type(4)));

#define LOG2E 1.44269504f
__device__ __forceinline__ float fexp2_(float x){ return __builtin_amdgcn_exp2f(x); }
__device__ __forceinline__ float frcp_(float x){ return __builtin_amdgcn_rcpf(x); }
__device__ __forceinline__ float fsig_(float x){ return frcp_(1.f + fexp2_(-LOG2E*x)); }
__device__ __forceinline__ float ftanh_(float x){ float t = fexp2_(2.f*LOG2E*x); return 1.f - 2.f*frcp_(t+1.f); }
__device__ __forceinline__ float felu_(float x){ return (x>0.f)? x : (fexp2_(LOG2E*x)-1.f); }

// async global->LDS 16B: per-lane global addr, wave-uniform LDS base (+lane*16 implicit)
__device__ __forceinline__ void load_lds16(const void* g, void* l){
  __builtin_amdgcn_global_load_lds((const __attribute__((address_space(1))) void*)g,
                                   (__attribute__((address_space(3))) void*)l, 16, 0, 0);
}

// BK=64 swizzle: tile = rows x 8 granules(16B). granule (row,kg) at slot row*8 + (kg ^ (row&7)).
// b128 frag read: 16-lane phase covers rows r..r+15 at fixed g -> bank-groups hit 2x each (free).
__device__ __forceinline__ bf16x8 lds_frag64(const __bf16* Ls, int rowbase, int lane, int kk){
  int row = rowbase + (lane&15);
  int g = (lane>>4) + (kk<<2);
  int slot = (row<<3) + (g ^ (row&7));
  return *(const bf16x8*)&Ls[slot<<3];
}

// ---------------- converts / prep ----------------
__global__ void cvt_h_kernel(const float* __restrict__ src, __bf16* __restrict__ Acat){
  int i = blockIdx.x*blockDim.x + threadIdx.x;   // over NNODES*64
  if (i >= NNODES*64) return;
  int row = i>>6, c = (i&63)<<2;
  float4 v = *(const float4*)&src[(size_t)row*HDIM + c];
  bf16x4 o; o[0]=(__bf16)v.x; o[1]=(__bf16)v.y; o[2]=(__bf16)v.z; o[3]=(__bf16)v.w;
  *(bf16x4*)&Acat[(size_t)row*KCAT + 256 + c] = o;
}

// merged weight prep: Bf[1024][512] + wgb[256][256] + lwb[128][256]
__global__ void prep_w_kernel(const float* __restrict__ Wih, const float* __restrict__ Whh,
                              const float* __restrict__ Wg, const float* __restrict__ Lw,
                              __bf16* __restrict__ Bf, __bf16* __restrict__ wgb,
                              __bf16* __restrict__ lwb){
  int i = blockIdx.x*blockDim.x + threadIdx.x;
  if (i < 1024*128){
    int row = i>>7, kc = (i&127)<<2;
    int gate = row>>8, c = row&255;
    float4 v = make_float4(0,0,0,0);
    if (gate==0 || gate==1){
      v = (kc<256) ? *(const float4*)&Wih[(size_t)(gate*256+c)*HDIM + kc]
                   : *(const float4*)&Whh[(size_t)(gate*256+c)*HDIM + kc-256];
    } else if (gate==2){
      if (kc<256) v = *(const float4*)&Wih[(size_t)(512+c)*HDIM + kc];
    } else {
      if (kc>=256) v = *(const float4*)&Whh[(size_t)(512+c)*HDIM + kc-256];
    }
    bf16x4 o; o[0]=(__bf16)v.x; o[1]=(__bf16)v.y; o[2]=(__bf16)v.z; o[3]=(__bf16)v.w;
    *(bf16x4*)&Bf[(size_t)row*KCAT + kc] = o;
  } else if (i < 1024*128 + 256*64){
    int j = i - 1024*128;
    float4 v = ((const float4*)Wg)[j];
    bf16x4 o; o[0]=(__bf16)v.x; o[1]=(__bf16)v.y; o[2]=(__bf16)v.z; o[3]=(__bf16)v.w;
    ((bf16x4*)wgb)[j] = o;
  } else if (i < 1024*128 + 256*64 + 128*64){
    int j = i - 1024*128 - 256*64;
    float4 v = ((const float4*)Lw)[j];
    bf16x4 o; o[0]=(__bf16)v.x; o[1]=(__bf16)v.y; o[2]=(__bf16)v.z; o[3]=(__bf16)v.w;
    ((bf16x4*)lwb)[j] = o;
  }
}

// ---------------- CSR build ----------------
__global__ void hist_kernel(const int* __restrict__ dst, int* __restrict__ deg){
  int e = blockIdx.x*blockDim.x + threadIdx.x;
  if (e < NEDGES) atomicAdd(&deg[dst[e]], 1);
}

__global__ void scan_kernel(const int* __restrict__ deg, int* __restrict__ rowptr){
  __shared__ int sdata[1024];
  __shared__ int s_carry;
  int tx = threadIdx.x;
  if (tx==0) s_carry = 0;
  __syncthreads();
  for (int base=0; base<NNODES; base+=1024){
    int i = base+tx;
    int v = (i<NNODES)? deg[i] : 0;
    sdata[tx]=v; __syncthreads();
    #pragma unroll
    for (int off=1; off<1024; off<<=1){
      int t = (tx>=off)? sdata[tx-off] : 0;
      __syncthreads();
      sdata[tx] += t;
      __syncthreads();
    }
    if (i<NNODES) rowptr[i] = s_carry + sdata[tx] - v;
    int tot = sdata[1023];
    __syncthreads();
    if (tx==0) s_carry += tot;
    __syncthreads();
  }
  if (tx==0) rowptr[NNODES] = s_carry;
}

__global__ void scatter_kernel(const int* __restrict__ src, const int* __restrict__ dst,
                               const int* __restrict__ rowptr, int* __restrict__ fill,
                               int* __restrict__ ssrc){
  int e = blockIdx.x*blockDim.x + threadIdx.x;
  if (e < NEDGES){
    int d = dst[e];
    int pos = rowptr[d] + atomicAdd(&fill[d], 1);
    ssrc[pos] = src[e];
  }
}

// ---------------- BK=64 LDS-staged MFMA GEMM: C[M,Nc] = A[M,256] @ B[Nc,256]^T ----------------
// 128 x NT tile, 4 waves, wave tile 64 x NT/2. YC = column-block count (linearized grid).
template<int NT, int YC, bool F32OUT>
__global__ __launch_bounds__(256,2)
void mfma_gemm64(const __bf16* __restrict__ A, int lda,
                 const __bf16* __restrict__ B,
                 const float* __restrict__ bias,
                 __bf16* __restrict__ Cb, float* __restrict__ Cf,
                 int ldc, int Mreal){
  constexpr int CF = NT/32;                // col frags per wave
  __shared__ __bf16 As[128*64];
  __shared__ __bf16 Bs[NT*64];
  int bid = blockIdx.x;
  int r0 = (bid/YC)*128, c0 = (bid%YC)*NT;
  int tx = threadIdx.x, lane = tx&63, w = tx>>6;
  f32x4 acc[4][CF] = {};
  for (int k0=0; k0<HDIM; k0+=64){
    #pragma unroll
    for (int q=0;q<4;q++){                 // A: 1024 slots
      int idx = q*256 + w*64 + lane;
      int row = idx>>3, kg = (idx&7) ^ (row&7);
      load_lds16(A + (size_t)(r0+row)*lda + k0 + (kg<<3),
                 (char*)As + (q*256 + w*64)*16);
    }
    #pragma unroll
    for (int q=0;q<NT/32;q++){             // B: NT*8 slots
      int idx = q*256 + w*64 + lane;
      int row = idx>>3, kg = (idx&7) ^ (row&7);
      load_lds16(B + (size_t)(c0+row)*HDIM + k0 + (kg<<3),
                 (char*)Bs + (q*256 + w*64)*16);
    }
    __syncthreads();
    int rbase = (w&1)*64, cbase = (w>>1)*(NT/2);
    #pragma unroll
    for (int kk=0;kk<2;kk++){
      bf16x8 a[4], b[CF];
      #pragma unroll
      for (int i=0;i<4;i++) a[i] = lds_frag64(As, rbase + i*16, lane, kk);
      #pragma unroll
      for (int j=0;j<CF;j++) b[j] = lds_frag64(Bs, cbase + j*16, lane, kk);
      #pragma unroll
      for (int i=0;i<4;i++)
        #pragma unroll
        for (int j=0;j<CF;j++)
          acc[i][j] = __builtin_amdgcn_mfma_f32_16x16x32_bf16(a[i], b[j], acc[i][j], 0,0,0);
    }
    __syncthreads();
  }
  int rbase = r0 + (w&1)*64, cbase = c0 + (w>>1)*(NT/2);
  #pragma unroll
  for (int i=0;i<4;i++){
    #pragma unroll
    for (int j=0;j<CF;j++){
      int gc = cbase + j*16 + (lane&15);
      float bv = F32OUT ? bias[gc] : 0.f;
      #pragma unroll
      for (int r=0;r<4;r++){
        int gr = rbase + i*16 + ((lane>>4)<<2) + r;
        if (gr >= Mreal) continue;
        float v = acc[i][j][r] + bv;
        if (F32OUT) Cf[(size_t)gr*ldc + gc] = v;
        else        Cb[(size_t)gr*ldc + gc] = (__bf16)v;
      }
    }
  }
}

// ---------------- attention logits ----------------
__global__ void alpha_kernel(const __bf16* __restrict__ xpb, const float* __restrict__ att_src,
                             const float* __restrict__ att_dst,
                             float* __restrict__ as_, float* __restrict__ ad_){
  int node = blockIdx.x*4 + (threadIdx.x>>6);
  int lane = threadIdx.x & 63;
  if (node >= NNODES) return;
  bf16x4 v4 = *(const bf16x4*)&xpb[(size_t)node*HDIM + lane*4];
  float4 a = *(const float4*)&att_src[lane*4];
  float4 b = *(const float4*)&att_dst[lane*4];
  float v0=(float)v4[0], v1=(float)v4[1], v2=(float)v4[2], v3=(float)v4[3];
  float ps = v0*a.x + v1*a.y + v2*a.z + v3*a.w;
  float pd = v0*b.x + v1*b.y + v2*b.z + v3*b.w;
  for (int off=32; off; off>>=1){ ps += __shfl_down(ps,off); pd += __shfl_down(pd,off); }
  if (lane==0){ as_[node]=ps; ad_[node]=pd; }
}

// ---------------- GAT softmax+aggregate: one wave/node, 32 lanes/row, 2 edges/load ----------------
__global__ __launch_bounds__(256)
void gat_aggregate_kernel(const __bf16* __restrict__ xpb, const float* __restrict__ as_,
                          const float* __restrict__ ad_, const int* __restrict__ rowptr,
                          const int* __restrict__ ssrc, const float* __restrict__ gat_bias,
                          __bf16* __restrict__ Acat){
  int node = blockIdx.x*4 + (threadIdx.x>>6);
  int lane = threadIdx.x & 63;
  if (node >= NNODES) return;
  int beg = rowptr[node], end = rowptr[node+1];
  int deg = end - beg;
  float adv = ad_[node];
  int half = lane>>5, col = lane&31;

  float acc[8] = {0,0,0,0,0,0,0,0};

  if (deg <= 64){
    float a = -INFINITY; int sreg = 0;
    if (lane < deg){
      sreg = ssrc[beg+lane];
      a = as_[sreg] + adv;
      a = (a>0.f)? a : 0.01f*a;
    }
    float mx = a;
    #pragma unroll
    for (int off=32; off; off>>=1) mx = fmaxf(mx, __shfl_xor(mx,off));
    float e = (lane<deg)? fexp2_(LOG2E*(a-mx)) : 0.f;
    float sm = e;
    #pragma unroll
    for (int off=32; off; off>>=1) sm += __shfl_xor(sm,off);
    float creg = e*frcp_(fmaxf(sm,1e-16f));

    int j = 0;
    for (; j+8<=deg; j+=8){
      float c0=__shfl(creg,j+0+half), c1=__shfl(creg,j+2+half),
            c2=__shfl(creg,j+4+half), c3=__shfl(creg,j+6+half);
      int   r0=__shfl(sreg,j+0+half), r1=__shfl(sreg,j+2+half),
            r2=__shfl(sreg,j+4+half), r3=__shfl(sreg,j+6+half);
      bf16x8 v0 = *(const bf16x8*)&xpb[(size_t)r0*HDIM + col*8];
      bf16x8 v1 = *(const bf16x8*)&xpb[(size_t)r1*HDIM + col*8];
      bf16x8 v2 = *(const bf16x8*)&xpb[(size_t)r2*HDIM + col*8];
      bf16x8 v3 = *(const bf16x8*)&xpb[(size_t)r3*HDIM + col*8];
      #pragma unroll
      for (int t=0;t<8;t++)
        acc[t] += c0*(float)v0[t] + c1*(float)v1[t] + c2*(float)v2[t] + c3*(float)v3[t];
    }
    for (; j<deg; j+=2){
      int jj = j + half;
      float cf = __shfl(creg, jj);
      int   rw = __shfl(sreg, jj);
      if (jj < deg){
        bf16x8 v = *(const bf16x8*)&xpb[(size_t)rw*HDIM + col*8];
        #pragma unroll
        for (int t=0;t<8;t++) acc[t] += cf*(float)v[t];
      }
    }
  } else {
    float mx = -INFINITY;
    for (int e=beg+lane; e<end; e+=64){
      float a = as_[ssrc[e]] + adv;
      a = (a>0.f)? a : 0.01f*a;
      mx = fmaxf(mx, a);
    }
    #pragma unroll
    for (int off=32; off; off>>=1) mx = fmaxf(mx, __shfl_xor(mx,off));
    float sm = 0.f;
    for (int e=beg+lane; e<end; e+=64){
      float a = as_[ssrc[e]] + adv;
      a = (a>0.f)? a : 0.01f*a;
      sm += fexp2_(LOG2E*(a-mx));
    }
    #pragma unroll
    for (int off=32; off; off>>=1) sm += __shfl_xor(sm,off);
    float rsc = frcp_(fmaxf(sm,1e-16f));
    for (int j=0; j<deg; j+=2){
      int jj = j + half;
      if (jj < deg){
        int rw = ssrc[beg+jj];
        float a = as_[rw] + adv;
        a = (a>0.f)? a : 0.01f*a;
        float cf = fexp2_(LOG2E*(a-mx))*rsc;
        bf16x8 v = *(const bf16x8*)&xpb[(size_t)rw*HDIM + col*8];
        #pragma unroll
        for (int t=0;t<8;t++) acc[t] += cf*(float)v[t];
      }
    }
  }

  #pragma unroll
  for (int t=0;t<8;t++) acc[t] += __shfl_down(acc[t], 32);
  if (half==0){
    float4 b0 = *(const float4*)&gat_bias[col*8];
    float4 b1 = *(const float4*)&gat_bias[col*8+4];
    float bb[8] = {b0.x,b0.y,b0.z,b0.w,b1.x,b1.y,b1.z,b1.w};
    bf16x8 ov;
    #pragma unroll
    for (int t=0;t<8;t++) ov[t] = (__bf16)felu_(acc[t]+bb[t]);
    *(bf16x8*)&Acat[(size_t)node*KCAT + col*8] = ov;   // msg slot
  }
}

// ---------------- fused GRU: Acat @ Bfused^T + GRU epilogue (BK=64, linearized grid) ----------------
__global__ __launch_bounds__(256,2)
void gru_mfma_kernel(const __bf16* __restrict__ Acat, __bf16* __restrict__ AcatN,
                     const __bf16* __restrict__ Bf,
                     const float* __restrict__ bih, const float* __restrict__ bhh){
  __shared__ __bf16 As[128*64];
  __shared__ __bf16 Bs[256*64];
  int bid = blockIdx.x;
  int r0 = (bid>>2)*128, c0 = (bid&3)*64;
  int tx = threadIdx.x, lane = tx&63, w = tx>>6;
  f32x4 acc[4][4][2] = {};   // [gate][rowfrag][colfrag]
  for (int k0=0; k0<KCAT; k0+=64){
    #pragma unroll
    for (int q=0;q<4;q++){                 // A: 1024 slots
      int idx = q*256 + w*64 + lane;
      int row = idx>>3, kg = (idx&7) ^ (row&7);
      load_lds16(Acat + (size_t)(r0+row)*KCAT + k0 + (kg<<3),
                 (char*)As + (q*256 + w*64)*16);
    }
    #pragma unroll
    for (int q=0;q<8;q++){                 // B: 2048 slots
      int idx = q*256 + w*64 + lane;
      int row = idx>>3, kg = (idx&7) ^ (row&7);
      int gate = row>>6, colr = row&63;
      load_lds16(Bf + (size_t)(gate*256 + c0 + colr)*KCAT + k0 + (kg<<3),
                 (char*)Bs + (q*256 + w*64)*16);
    }
    __syncthreads();
    int rbase = (w&1)*64, cbase = (w>>1)*32;
    #pragma unroll
    for (int kk=0;kk<2;kk++){
      bf16x8 a[4], b[4][2];
      #pragma unroll
      for (int i=0;i<4;i++) a[i] = lds_frag64(As, rbase + i*16, lane, kk);
      #pragma unroll
      for (int g=0;g<4;g++)
        #pragma unroll
        for (int j=0;j<2;j++) b[g][j] = lds_frag64(Bs, g*64 + cbase + j*16, lane, kk);
      #pragma unroll
      for (int g=0;g<4;g++)
        #pragma unroll
        for (int i=0;i<4;i++)
          #pragma unroll
          for (int j=0;j<2;j++)
            acc[g][i][j] = __builtin_amdgcn_mfma_f32_16x16x32_bf16(a[i], b[g][j], acc[g][i][j], 0,0,0);
    }
    __syncthreads();
  }
  int rbase = r0 + (w&1)*64, cb = (w>>1)*32;
  #pragma unroll
  for (int i=0;i<4;i++){
    #pragma unroll
    for (int j=0;j<2;j++){
      int gc = c0 + cb + j*16 + (lane&15);
      float br_ = bih[gc]     + bhh[gc];
      float bz_ = bih[256+gc] + bhh[256+gc];
      float bnx = bih[512+gc];
      float bnh = bhh[512+gc];
      #pragma unroll
      for (int r=0;r<4;r++){
        int gr = rbase + i*16 + ((lane>>4)<<2) + r;
        if (gr >= NNODES) continue;
        float hold = (float)Acat[(size_t)gr*KCAT + 256 + gc];
        float rr = fsig_(acc[0][i][j][r] + br_);
        float zz = fsig_(acc[1][i][j][r] + bz_);
        float nn = ftanh_(acc[2][i][j][r] + bnx + rr*(acc[3][i][j][r] + bnh));
        AcatN[(size_t)gr*KCAT + 256 + gc] = (__bf16)((1.f-zz)*nn + zz*hold);
      }
    }
  }
}

// ---------------- launch ----------------
extern "C" void kernel_launch(void* const* d_in, const int* in_sizes, int n_in,
                              void* d_out, int out_size, void* d_ws, size_t ws_size,
                              hipStream_t stream) {
  const float* x_clique = (const float*)d_in[0];
  const float* W_gat    = (const float*)d_in[1];
  const float* att_src  = (const float*)d_in[2];
  const float* att_dst  = (const float*)d_in[3];
  const float* gat_bias = (const float*)d_in[4];
  const float* W_ih     = (const float*)d_in[5];
  const float* W_hh     = (const float*)d_in[6];
  const float* b_ih     = (const float*)d_in[7];
  const float* b_hh     = (const float*)d_in[8];
  const float* lin_W    = (const float*)d_in[9];
  const float* lin_b    = (const float*)d_in[10];
  const int*   eidx     = (const int*)d_in[14];
  float* out = (float*)d_out;

  const int* src = eidx;
  const int* dst = eidx + NEDGES;

  const size_t ACAT = (size_t)NROWP*KCAT;
  __bf16* AcA  = (__bf16*)d_ws;
  __bf16* AcB  = AcA + ACAT;
  __bf16* xpb  = AcB + ACAT;                        // [NROWP][256]
  __bf16* Bf   = xpb + (size_t)NROWP*HDIM;          // [1024][512]
  __bf16* wgb  = Bf  + (size_t)1024*KCAT;           // [256][256]
  __bf16* lwb  = wgb + (size_t)HDIM*HDIM;           // [128][256]
  float* as_   = (float*)(lwb + (size_t)ODIM*HDIM);
  float* ad_   = as_ + NNODES;
  int* deg     = (int*)(ad_ + NNODES);
  int* fill    = deg + NNODES;
  int* rowptr  = fill + NNODES;
  int* ssrc    = rowptr + (NNODES+1);

  // CSR build
  hipMemsetAsync(deg,  0, NNODES*sizeof(int), stream);
  hipMemsetAsync(fill, 0, NNODES*sizeof(int), stream);
  hist_kernel<<<(NEDGES+255)/256, 256, 0, stream>>>(dst, deg);
  scan_kernel<<<1, 1024, 0, stream>>>(deg, rowptr);
  scatter_kernel<<<(NEDGES+255)/256, 256, 0, stream>>>(src, dst, rowptr, fill, ssrc);

  // weight preps
  cvt_h_kernel<<<(NNODES*64+255)/256, 256, 0, stream>>>(x_clique, AcA);
  prep_w_kernel<<<(1024*128 + 256*64 + 128*64 + 255)/256, 256, 0, stream>>>(
      W_ih, W_hh, W_gat, lin_W, Bf, wgb, lwb);

  const int RB = NROWP/128;   // 157
  __bf16* Ac = AcA;
  __bf16* An = AcB;
  for (int t=0; t<TSTEPS; t++){
    mfma_gemm64<128,2,false><<<RB*2, 256, 0, stream>>>(
        Ac + 256, KCAT, wgb, nullptr, xpb, nullptr, HDIM, NNODES);
    alpha_kernel<<<(NNODES+3)/4, 256, 0, stream>>>(xpb, att_src, att_dst, as_, ad_);
    gat_aggregate_kernel<<<(NNODES+3)/4, 256, 0, stream>>>(xpb, as_, ad_, rowptr, ssrc, gat_bias, Ac);
    gru_mfma_kernel<<<RB*4, 256, 0, stream>>>(Ac, An, Bf, b_ih, b_hh);
    __bf16* tmp = Ac; Ac = An; An = tmp;
  }
  mfma_gemm64<128,1,true><<<RB, 256, 0, stream>>>(
      Ac + 256, KCAT, lwb, lin_b, nullptr, out, ODIM, NNODES);
}